// Round 1
// baseline (356.599 us; speedup 1.0000x reference)
//
#include <hip/hip_runtime.h>
#include <math.h>

// Problem constants
// B=32, OBS=768, D=512, V=64
// Outputs (f32, concatenated): h[32*512] | pred[32*768] | graph[64*64] | reasoning[32*512]

__device__ __forceinline__ float gelu_exact(float x) {
    return 0.5f * x * (1.f + erff(x * 0.70710678118654752f));
}

// Fast gelu (tanh approx in sigmoid form): x * sigmoid(1.5957691216 x + 0.0713548163 x^3)
__device__ __forceinline__ float gelu_fast(float x) {
    float x2 = x * x;
    float arg = x * fmaf(x2, -0.0713548163f, -1.5957691216f); // = -(2u)
    float t = __expf(arg);                                    // exp(-2u)
    return x * __builtin_amdgcn_rcpf(1.0f + t);               // x * sigmoid(2u)
}

__device__ __forceinline__ float sigmoidf_fast(float v) {
    return 1.f / (1.f + __expf(-v));
}

// out[b][o] = act( dot(A[b,:], W[o,:]) + bias[o] )
// 4 lanes cooperate per output (sub = tid&3 splits K in 4 chunks).
// Grid must be exactly M*N*4/256 blocks of 256 threads.
__global__ void dot_s4(const float* __restrict__ A, int lda,
                       const float* __restrict__ W, int ldw,
                       const float* __restrict__ bias,
                       float* __restrict__ out, int ldo,
                       int M, int K, int act) {
    int tid = blockIdx.x * 256 + threadIdx.x;
    int sub = tid & 3;
    int group = tid >> 2;
    int b = group % M;
    int o = group / M;
    int KS = K >> 2;  // floats per sub-chunk
    const float4* a4 = reinterpret_cast<const float4*>(A + b * lda + sub * KS);
    const float4* w4 = reinterpret_cast<const float4*>(W + o * ldw + sub * KS);
    float acc = 0.f;
    int n4 = KS >> 2;
#pragma unroll 8
    for (int k = 0; k < n4; ++k) {
        float4 a = a4[k];
        float4 w = w4[k];
        acc += a.x * w.x + a.y * w.y + a.z * w.z + a.w * w.w;
    }
    acc += __shfl_xor(acc, 1, 64);
    acc += __shfl_xor(acc, 2, 64);
    if (sub == 0) {
        float v = acc + (bias ? bias[o] : 0.f);
        if (act == 1) v = gelu_exact(v);
        out[b * ldo + o] = v;
    }
}

// x[:, 512:1024] = action  (x row stride 1024)
__global__ void prep_x(const float* __restrict__ action, float* __restrict__ x) {
    int tid = blockIdx.x * 256 + threadIdx.x;  // 16384
    int b = tid >> 9;
    int c = tid & 511;
    x[b * 1024 + 512 + c] = action[tid];
}

// GRU update with h0 = 0: gh = bhh.
__global__ void gru_kernel(const float* __restrict__ gi, const float* __restrict__ bhh,
                           const float* __restrict__ action,
                           float* __restrict__ h, float* __restrict__ ha) {
    int tid = blockIdx.x * 256 + threadIdx.x;  // 16384 = 32*512
    int b = tid >> 9;
    int o = tid & 511;
    const float* g = gi + b * 1536;
    float r = 1.f / (1.f + expf(-(g[o] + bhh[o])));
    float u = 1.f / (1.f + expf(-(g[512 + o] + bhh[512 + o])));
    float n = tanhf(g[1024 + o] + r * bhh[1024 + o]);
    float hv = (1.f - u) * n;
    h[tid] = hv;
    ha[tid] = hv + action[tid];
}

// graph[i][j] = mean_b sigmoid( sum_d gelu(Cc[b,d]+Ea'[i,d]+Eb[j,d]) * w2[d] + b2 )
// Ea' already includes sc_b1. One block per (i, j0..j0+1). wave w handles b in [8w,8w+8);
// lane owns d in [lane*16, lane*16+16).
__global__ void __launch_bounds__(256) score_kernel(
    const float* __restrict__ Ea, const float* __restrict__ Eb,
    const float* __restrict__ Cc, const float* __restrict__ w2,
    const float* __restrict__ b2, float* __restrict__ graph) {
    int i = blockIdx.x >> 5;
    int j0 = (blockIdx.x & 31) << 1;
    int lane = threadIdx.x & 63;
    int wave = threadIdx.x >> 6;
    int d0 = lane << 4;

    const float4* Ea4  = reinterpret_cast<const float4*>(Ea + i * 1024 + d0);
    const float4* Eb04 = reinterpret_cast<const float4*>(Eb + j0 * 1024 + d0);
    const float4* Eb14 = reinterpret_cast<const float4*>(Eb + (j0 + 1) * 1024 + d0);
    const float4* W4   = reinterpret_cast<const float4*>(w2 + d0);

    float basea[16], baseb[16], wv[16];
#pragma unroll
    for (int c = 0; c < 4; ++c) {
        float4 e  = Ea4[c];
        float4 f0 = Eb04[c];
        float4 f1 = Eb14[c];
        float4 w  = W4[c];
        basea[4 * c + 0] = e.x + f0.x; basea[4 * c + 1] = e.y + f0.y;
        basea[4 * c + 2] = e.z + f0.z; basea[4 * c + 3] = e.w + f0.w;
        baseb[4 * c + 0] = e.x + f1.x; baseb[4 * c + 1] = e.y + f1.y;
        baseb[4 * c + 2] = e.z + f1.z; baseb[4 * c + 3] = e.w + f1.w;
        wv[4 * c + 0] = w.x; wv[4 * c + 1] = w.y;
        wv[4 * c + 2] = w.z; wv[4 * c + 3] = w.w;
    }

    float acc0[8], acc1[8];
    for (int r = 0; r < 8; ++r) {
        const float4* cc4 = reinterpret_cast<const float4*>(Cc + (wave * 8 + r) * 1024 + d0);
        float cc[16];
#pragma unroll
        for (int c = 0; c < 4; ++c) {
            float4 v = cc4[c];
            cc[4 * c + 0] = v.x; cc[4 * c + 1] = v.y;
            cc[4 * c + 2] = v.z; cc[4 * c + 3] = v.w;
        }
        float s0 = 0.f, s1 = 0.f;
#pragma unroll
        for (int e = 0; e < 16; ++e) {
            s0 += gelu_fast(cc[e] + basea[e]) * wv[e];
            s1 += gelu_fast(cc[e] + baseb[e]) * wv[e];
        }
        acc0[r] = s0;
        acc1[r] = s1;
    }

    float bsc = b2[0];
    float sum0 = 0.f, sum1 = 0.f;
#pragma unroll
    for (int r = 0; r < 8; ++r) {
        float v0 = acc0[r], v1 = acc1[r];
#pragma unroll
        for (int m = 32; m >= 1; m >>= 1) {
            v0 += __shfl_xor(v0, m, 64);
            v1 += __shfl_xor(v1, m, 64);
        }
        if (lane == 0) {
            sum0 += sigmoidf_fast(v0 + bsc);
            sum1 += sigmoidf_fast(v1 + bsc);
        }
    }

    __shared__ float red[4][2];
    if (lane == 0) { red[wave][0] = sum0; red[wave][1] = sum1; }
    __syncthreads();
    if (threadIdx.x == 0) {
        float g0 = (red[0][0] + red[1][0] + red[2][0] + red[3][0]) * 0.03125f;
        float g1 = (red[0][1] + red[1][1] + red[2][1] + red[3][1]) * 0.03125f;
        graph[i * 64 + j0] = g0;
        graph[i * 64 + j0 + 1] = g1;
    }
}

extern "C" void kernel_launch(void* const* d_in, const int* in_sizes, int n_in,
                              void* d_out, int out_size, void* d_ws, size_t ws_size,
                              hipStream_t stream) {
    const float* obs     = (const float*)d_in[0];   // 32x768
    const float* action  = (const float*)d_in[1];   // 32x512
    const float* embed   = (const float*)d_in[2];   // 64x512
    const float* sc_w1   = (const float*)d_in[3];   // 1024x1536
    const float* sc_b1   = (const float*)d_in[4];   // 1024
    const float* sc_w2   = (const float*)d_in[5];   // 1x1024
    const float* sc_b2   = (const float*)d_in[6];   // 1
    const float* enc_w1  = (const float*)d_in[7];   // 1024x768
    const float* enc_b1  = (const float*)d_in[8];   // 1024
    const float* enc_w2  = (const float*)d_in[9];   // 512x1024
    const float* enc_b2  = (const float*)d_in[10];  // 512
    const float* gru_wih = (const float*)d_in[11];  // 1536x1024
    // d_in[12] = gru_whh (unused: h0 == 0)
    const float* gru_bih = (const float*)d_in[13];  // 1536
    const float* gru_bhh = (const float*)d_in[14];  // 1536
    const float* dec_w   = (const float*)d_in[15];  // 768x512
    const float* dec_b   = (const float*)d_in[16];  // 768
    const float* rs_w1   = (const float*)d_in[17];  // 512x512
    const float* rs_b1   = (const float*)d_in[18];  // 512
    const float* rs_w2   = (const float*)d_in[19];  // 512x512
    const float* rs_b2   = (const float*)d_in[20];  // 512

    float* ws = (float*)d_ws;
    float* x       = ws + 0;       // 32x1024  (z || action)
    float* hidden1 = ws + 32768;   // 32x1024
    float* gi      = ws + 65536;   // 32x1536
    float* ha      = ws + 114688;  // 32x512   (h + action)
    float* r1      = ws + 131072;  // 32x512
    float* Cc      = ws + 147456;  // 32x1024
    float* Ea      = ws + 180224;  // 64x1024  (incl. sc_b1)
    float* Eb      = ws + 245760;  // 64x1024

    float* h_out      = (float*)d_out;        // 32x512
    float* pred       = h_out + 16384;        // 32x768
    float* graph      = h_out + 40960;        // 64x64
    float* reasoning  = h_out + 45056;        // 32x512

    // independent of h: x tail, encoder chain, Ea/Eb
    prep_x<<<64, 256, 0, stream>>>(action, x);
    dot_s4<<<512, 256, 0, stream>>>(obs, 768, enc_w1, 768, enc_b1, hidden1, 1024, 32, 768, 1);
    dot_s4<<<256, 256, 0, stream>>>(hidden1, 1024, enc_w2, 1024, enc_b2, x, 1024, 32, 1024, 0);
    dot_s4<<<768, 256, 0, stream>>>(x, 1024, gru_wih, 1024, gru_bih, gi, 1536, 32, 1024, 0);
    gru_kernel<<<64, 256, 0, stream>>>(gi, gru_bhh, action, h_out, ha);
    dot_s4<<<384, 256, 0, stream>>>(h_out, 512, dec_w, 512, dec_b, pred, 768, 32, 512, 0);
    dot_s4<<<256, 256, 0, stream>>>(h_out, 512, rs_w1, 512, rs_b1, r1, 512, 32, 512, 1);
    dot_s4<<<256, 256, 0, stream>>>(r1, 512, rs_w2, 512, rs_b2, reasoning, 512, 32, 512, 0);
    dot_s4<<<512, 256, 0, stream>>>(ha, 512, sc_w1 + 1024, 1536, nullptr, Cc, 1024, 32, 512, 0);
    dot_s4<<<1024, 256, 0, stream>>>(embed, 512, sc_w1, 1536, sc_b1, Ea, 1024, 64, 512, 0);
    dot_s4<<<1024, 256, 0, stream>>>(embed, 512, sc_w1 + 512, 1536, nullptr, Eb, 1024, 64, 512, 0);
    score_kernel<<<2048, 256, 0, stream>>>(Ea, Eb, Cc, sc_w2, sc_b2, graph);
}

// Round 2
// 317.128 us; speedup vs baseline: 1.1245x; 1.1245x over previous
//
#include <hip/hip_runtime.h>
#include <math.h>

// B=32, OBS=768, D=512, V=64
// Outputs (f32): h[32*512] | pred[32*768] | graph[64*64] | reasoning[32*512]

#if __has_builtin(__builtin_amdgcn_exp2f)
#define EXP2F __builtin_amdgcn_exp2f
#else
#define EXP2F exp2f
#endif

__device__ __forceinline__ float gelu_exact(float x) {
    return 0.5f * x * (1.f + erff(x * 0.70710678118654752f));
}

// gelu tanh-approx in sigmoid form with log2(e) folded in:
// gelu(x) ~= x / (1 + 2^-(2.3022078 x + 0.1029434 x^3))
__device__ __forceinline__ float gelu_fast(float x) {
    float x2 = x * x;
    float arg = x * fmaf(x2, -0.1029434f, -2.3022078f);
    float t = EXP2F(arg);
    return x * __builtin_amdgcn_rcpf(1.0f + t);
}

__device__ __forceinline__ float sigmoidf_fast(float v) {
    return 1.f / (1.f + __expf(-v));
}

// out[b][o] = act( dot(A[b,:], W[o,:]) + bias[o] ); 4 lanes per output.
// M must be a power of two (mask = M-1, shift = log2 M).
__device__ __forceinline__ void dot_body(int tid,
        const float* __restrict__ A, int lda,
        const float* __restrict__ W, int ldw,
        const float* __restrict__ bias,
        float* __restrict__ out, int ldo,
        int mmask, int mlog2, int K, int act) {
    int sub = tid & 3;
    int group = tid >> 2;
    int b = group & mmask;
    int o = group >> mlog2;
    int KS = K >> 2;
    const float4* a4 = reinterpret_cast<const float4*>(A + b * lda + sub * KS);
    const float4* w4 = reinterpret_cast<const float4*>(W + o * ldw + sub * KS);
    float acc = 0.f;
    int n4 = KS >> 2;
#pragma unroll 8
    for (int k = 0; k < n4; ++k) {
        float4 a = a4[k];
        float4 w = w4[k];
        acc = fmaf(a.x, w.x, acc);
        acc = fmaf(a.y, w.y, acc);
        acc = fmaf(a.z, w.z, acc);
        acc = fmaf(a.w, w.w, acc);
    }
    acc += __shfl_xor(acc, 1, 64);
    acc += __shfl_xor(acc, 2, 64);
    if (sub == 0) {
        float v = acc + (bias ? bias[o] : 0.f);
        if (act) v = gelu_exact(v);
        out[b * ldo + o] = v;
    }
}

// K1: enc1 (512 blk) + Ea (1024 blk) + Eb (1024 blk) + action->x copy (64 blk) = 2624
__global__ void __launch_bounds__(256) front_kernel(
    const float* __restrict__ obs, const float* __restrict__ enc_w1,
    const float* __restrict__ enc_b1, float* __restrict__ h1,
    const float* __restrict__ embed, const float* __restrict__ sc_w1,
    const float* __restrict__ sc_b1, float* __restrict__ Ea, float* __restrict__ Eb,
    const float* __restrict__ action, float* __restrict__ x) {
    int blk = blockIdx.x, t = threadIdx.x;
    if (blk < 512) {
        dot_body(blk * 256 + t, obs, 768, enc_w1, 768, enc_b1, h1, 1024, 31, 5, 768, 1);
    } else if (blk < 1536) {
        dot_body((blk - 512) * 256 + t, embed, 512, sc_w1, 1536, sc_b1, Ea, 1024, 63, 6, 512, 0);
    } else if (blk < 2560) {
        dot_body((blk - 1536) * 256 + t, embed, 512, sc_w1 + 512, 1536, nullptr, Eb, 1024, 63, 6, 512, 0);
    } else {
        int id = (blk - 2560) * 256 + t;  // 16384
        x[(id >> 9) * 1024 + 512 + (id & 511)] = action[id];
    }
}

// K2: enc2 -> x[:, :512]  (256 blocks)
__global__ void __launch_bounds__(256) enc2_kernel(
    const float* __restrict__ h1, const float* __restrict__ enc_w2,
    const float* __restrict__ enc_b2, float* __restrict__ x) {
    dot_body(blockIdx.x * 256 + threadIdx.x, h1, 1024, enc_w2, 1024, enc_b2, x, 1024, 31, 5, 1024, 0);
}

// K3: gi GEMM + GRU fused. group=(b,o), 4 lanes each, 3 dots over K=1024. 256 blocks.
// h0 = 0 => gh = bhh.
__global__ void __launch_bounds__(256) gru_fused(
    const float* __restrict__ x, const float* __restrict__ wih,
    const float* __restrict__ bih, const float* __restrict__ bhh,
    const float* __restrict__ action, float* __restrict__ h, float* __restrict__ ha) {
    int tid = blockIdx.x * 256 + threadIdx.x;  // 65536
    int sub = tid & 3;
    int group = tid >> 2;      // 16384 = 32*512
    int b = group & 31;
    int o = group >> 5;
    const float4* a4 = reinterpret_cast<const float4*>(x + b * 1024 + sub * 256);
    const float4* w0 = reinterpret_cast<const float4*>(wih + o * 1024 + sub * 256);
    const float4* w1 = reinterpret_cast<const float4*>(wih + (512 + o) * 1024 + sub * 256);
    const float4* w2 = reinterpret_cast<const float4*>(wih + (1024 + o) * 1024 + sub * 256);
    float ar = 0.f, au = 0.f, an = 0.f;
#pragma unroll 4
    for (int k = 0; k < 64; ++k) {
        float4 a = a4[k];
        float4 p = w0[k], q = w1[k], s = w2[k];
        ar = fmaf(a.x, p.x, ar); ar = fmaf(a.y, p.y, ar); ar = fmaf(a.z, p.z, ar); ar = fmaf(a.w, p.w, ar);
        au = fmaf(a.x, q.x, au); au = fmaf(a.y, q.y, au); au = fmaf(a.z, q.z, au); au = fmaf(a.w, q.w, au);
        an = fmaf(a.x, s.x, an); an = fmaf(a.y, s.y, an); an = fmaf(a.z, s.z, an); an = fmaf(a.w, s.w, an);
    }
    ar += __shfl_xor(ar, 1, 64); ar += __shfl_xor(ar, 2, 64);
    au += __shfl_xor(au, 1, 64); au += __shfl_xor(au, 2, 64);
    an += __shfl_xor(an, 1, 64); an += __shfl_xor(an, 2, 64);
    if (sub == 0) {
        float r = 1.f / (1.f + expf(-(ar + bih[o] + bhh[o])));
        float u = 1.f / (1.f + expf(-(au + bih[512 + o] + bhh[512 + o])));
        float n = tanhf(an + bih[1024 + o] + r * bhh[1024 + o]);
        float hv = (1.f - u) * n;
        h[b * 512 + o] = hv;
        ha[b * 512 + o] = hv + action[b * 512 + o];
    }
}

// K4: dec (384 blk) + rs1 (256 blk) + Cc (512 blk) = 1152 blocks
__global__ void __launch_bounds__(256) mid_kernel(
    const float* __restrict__ h, const float* __restrict__ ha,
    const float* __restrict__ dec_w, const float* __restrict__ dec_b, float* __restrict__ pred,
    const float* __restrict__ rs_w1, const float* __restrict__ rs_b1, float* __restrict__ r1,
    const float* __restrict__ sc_w1, float* __restrict__ Cc) {
    int blk = blockIdx.x, t = threadIdx.x;
    if (blk < 384) {
        dot_body(blk * 256 + t, h, 512, dec_w, 512, dec_b, pred, 768, 31, 5, 512, 0);
    } else if (blk < 640) {
        dot_body((blk - 384) * 256 + t, h, 512, rs_w1, 512, rs_b1, r1, 512, 31, 5, 512, 1);
    } else {
        dot_body((blk - 640) * 256 + t, ha, 512, sc_w1 + 1024, 1536, nullptr, Cc, 1024, 31, 5, 512, 0);
    }
}

// K5: score (2048 blk: i = blk>>5, 2 j's) + rs2 (256 blk) = 2304 blocks
// Per block: wave w -> b in [8w,8w+8), lane -> d in [16*lane, 16*lane+16).
// Prefetches next Cc row while computing current.
__global__ void __launch_bounds__(256) score_rs2_kernel(
    const float* __restrict__ Ea, const float* __restrict__ Eb,
    const float* __restrict__ Cc, const float* __restrict__ w2,
    const float* __restrict__ b2, float* __restrict__ graph,
    const float* __restrict__ r1, const float* __restrict__ rs_w2,
    const float* __restrict__ rs_b2, float* __restrict__ reasoning) {
    int blk = blockIdx.x;
    if (blk >= 2048) {
        dot_body((blk - 2048) * 256 + threadIdx.x, r1, 512, rs_w2, 512, rs_b2, reasoning, 512, 31, 5, 512, 0);
        return;
    }
    int i = blk >> 5;
    int j0 = (blk & 31) << 1;
    int lane = threadIdx.x & 63;
    int wave = threadIdx.x >> 6;
    int d0 = lane << 4;

    const float4* Ea4  = reinterpret_cast<const float4*>(Ea + i * 1024 + d0);
    const float4* Eb04 = reinterpret_cast<const float4*>(Eb + j0 * 1024 + d0);
    const float4* Eb14 = reinterpret_cast<const float4*>(Eb + (j0 + 1) * 1024 + d0);
    const float4* W4   = reinterpret_cast<const float4*>(w2 + d0);

    float basea[16], baseb[16], wv[16];
#pragma unroll
    for (int c = 0; c < 4; ++c) {
        float4 e  = Ea4[c];
        float4 f0 = Eb04[c];
        float4 f1 = Eb14[c];
        float4 w  = W4[c];
        basea[4 * c + 0] = e.x + f0.x; basea[4 * c + 1] = e.y + f0.y;
        basea[4 * c + 2] = e.z + f0.z; basea[4 * c + 3] = e.w + f0.w;
        baseb[4 * c + 0] = e.x + f1.x; baseb[4 * c + 1] = e.y + f1.y;
        baseb[4 * c + 2] = e.z + f1.z; baseb[4 * c + 3] = e.w + f1.w;
        wv[4 * c + 0] = w.x; wv[4 * c + 1] = w.y;
        wv[4 * c + 2] = w.z; wv[4 * c + 3] = w.w;
    }

    float bsc = b2[0];
    float gsum0 = 0.f, gsum1 = 0.f;
    const float4* p = reinterpret_cast<const float4*>(Cc + (wave * 8) * 1024 + d0);
    float4 n0 = p[0], n1 = p[1], n2 = p[2], n3 = p[3];

    for (int r = 0; r < 8; ++r) {
        float cc[16];
        cc[0] = n0.x; cc[1] = n0.y; cc[2]  = n0.z; cc[3]  = n0.w;
        cc[4] = n1.x; cc[5] = n1.y; cc[6]  = n1.z; cc[7]  = n1.w;
        cc[8] = n2.x; cc[9] = n2.y; cc[10] = n2.z; cc[11] = n2.w;
        cc[12] = n3.x; cc[13] = n3.y; cc[14] = n3.z; cc[15] = n3.w;
        if (r < 7) {
            const float4* q = reinterpret_cast<const float4*>(Cc + (wave * 8 + r + 1) * 1024 + d0);
            n0 = q[0]; n1 = q[1]; n2 = q[2]; n3 = q[3];
        }
        float s0 = 0.f, s1 = 0.f;
#pragma unroll
        for (int e = 0; e < 16; ++e) {
            float c = cc[e], w = wv[e];
            s0 = fmaf(gelu_fast(c + basea[e]), w, s0);
            s1 = fmaf(gelu_fast(c + baseb[e]), w, s1);
        }
#pragma unroll
        for (int m = 32; m >= 1; m >>= 1) {
            s0 += __shfl_xor(s0, m, 64);
            s1 += __shfl_xor(s1, m, 64);
        }
        if (lane == 0) {
            gsum0 += sigmoidf_fast(s0 + bsc);
            gsum1 += sigmoidf_fast(s1 + bsc);
        }
    }

    __shared__ float red[4][2];
    if (lane == 0) { red[wave][0] = gsum0; red[wave][1] = gsum1; }
    __syncthreads();
    if (threadIdx.x == 0) {
        graph[i * 64 + j0]     = (red[0][0] + red[1][0] + red[2][0] + red[3][0]) * 0.03125f;
        graph[i * 64 + j0 + 1] = (red[0][1] + red[1][1] + red[2][1] + red[3][1]) * 0.03125f;
    }
}

extern "C" void kernel_launch(void* const* d_in, const int* in_sizes, int n_in,
                              void* d_out, int out_size, void* d_ws, size_t ws_size,
                              hipStream_t stream) {
    const float* obs     = (const float*)d_in[0];
    const float* action  = (const float*)d_in[1];
    const float* embed   = (const float*)d_in[2];
    const float* sc_w1   = (const float*)d_in[3];
    const float* sc_b1   = (const float*)d_in[4];
    const float* sc_w2   = (const float*)d_in[5];
    const float* sc_b2   = (const float*)d_in[6];
    const float* enc_w1  = (const float*)d_in[7];
    const float* enc_b1  = (const float*)d_in[8];
    const float* enc_w2  = (const float*)d_in[9];
    const float* enc_b2  = (const float*)d_in[10];
    const float* gru_wih = (const float*)d_in[11];
    const float* gru_bih = (const float*)d_in[13];
    const float* gru_bhh = (const float*)d_in[14];
    const float* dec_w   = (const float*)d_in[15];
    const float* dec_b   = (const float*)d_in[16];
    const float* rs_w1   = (const float*)d_in[17];
    const float* rs_b1   = (const float*)d_in[18];
    const float* rs_w2   = (const float*)d_in[19];
    const float* rs_b2   = (const float*)d_in[20];

    float* ws = (float*)d_ws;
    float* x       = ws + 0;       // 32x1024
    float* h1      = ws + 32768;   // 32x1024
    float* ha      = ws + 114688;  // 32x512
    float* r1      = ws + 131072;  // 32x512
    float* Cc      = ws + 147456;  // 32x1024
    float* Ea      = ws + 180224;  // 64x1024
    float* Eb      = ws + 245760;  // 64x1024

    float* h_out     = (float*)d_out;
    float* pred      = h_out + 16384;
    float* graph     = h_out + 40960;
    float* reasoning = h_out + 45056;

    front_kernel<<<2624, 256, 0, stream>>>(obs, enc_w1, enc_b1, h1,
                                           embed, sc_w1, sc_b1, Ea, Eb, action, x);
    enc2_kernel<<<256, 256, 0, stream>>>(h1, enc_w2, enc_b2, x);
    gru_fused<<<256, 256, 0, stream>>>(x, gru_wih, gru_bih, gru_bhh, action, h_out, ha);
    mid_kernel<<<1152, 256, 0, stream>>>(h_out, ha, dec_w, dec_b, pred,
                                         rs_w1, rs_b1, r1, sc_w1, Cc);
    score_rs2_kernel<<<2304, 256, 0, stream>>>(Ea, Eb, Cc, sc_w2, sc_b2, graph,
                                               r1, rs_w2, rs_b2, reasoning);
}

// Round 3
// 227.227 us; speedup vs baseline: 1.5694x; 1.3956x over previous
//
#include <hip/hip_runtime.h>
#include <math.h>

// B=32, OBS=768, D=512, V=64
// Outputs (f32): h[32*512] | pred[32*768] | graph[64*64] | reasoning[32*512]

#if __has_builtin(__builtin_amdgcn_exp2f)
#define EXP2F __builtin_amdgcn_exp2f
#else
#define EXP2F exp2f
#endif

__device__ __forceinline__ float gelu_exact(float x) {
    return 0.5f * x * (1.f + erff(x * 0.70710678118654752f));
}

// gelu tanh-approx in sigmoid form, log2(e) folded:
// gelu(x) ~= x / (1 + 2^-(2.3022078 x + 0.1029434 x^3))
__device__ __forceinline__ float gelu_fast(float x) {
    float x2 = x * x;
    float arg = x * fmaf(x2, -0.1029434f, -2.3022078f);
    float t = EXP2F(arg);
    return x * __builtin_amdgcn_rcpf(1.0f + t);
}

__device__ __forceinline__ float sigmoidf_fast(float v) {
    return 1.f / (1.f + __expf(-v));
}

// Wave-tile GEMM: one wave computes out[b0..b0+7][o0..o0+7] = act(A[b,:]·W[o,:] + bias[o]).
// K = NF4*256 floats. Lane owns float4 indices {c*64+lane}. ALL global loads coalesced
// (64 lanes x consecutive float4 = 1KB/instr). 6-stage butterfly reduce, 8-way ILP.
template<int NF4, int ACT>
__device__ __forceinline__ void wgemm(int wid,
        const float* __restrict__ A, int lda,
        const float* __restrict__ W, int ldw,
        const float* __restrict__ bias,
        float* __restrict__ out, int ldo,
        int oblocks) {
    int lane = threadIdx.x & 63;
    int oblock = wid % oblocks;
    int bgroup = wid / oblocks;
    int o0 = oblock * 8, b0 = bgroup * 8;

    float4 w[8][NF4];
#pragma unroll
    for (int r = 0; r < 8; ++r) {
        const float4* wr = reinterpret_cast<const float4*>(W + (o0 + r) * ldw);
#pragma unroll
        for (int c = 0; c < NF4; ++c) w[r][c] = wr[c * 64 + lane];
    }

#pragma unroll 2
    for (int bi = 0; bi < 8; ++bi) {
        const float4* ar = reinterpret_cast<const float4*>(A + (b0 + bi) * lda);
        float4 a[NF4];
#pragma unroll
        for (int c = 0; c < NF4; ++c) a[c] = ar[c * 64 + lane];
        float s[8];
#pragma unroll
        for (int r = 0; r < 8; ++r) {
            float acc = 0.f;
#pragma unroll
            for (int c = 0; c < NF4; ++c) {
                acc = fmaf(a[c].x, w[r][c].x, acc);
                acc = fmaf(a[c].y, w[r][c].y, acc);
                acc = fmaf(a[c].z, w[r][c].z, acc);
                acc = fmaf(a[c].w, w[r][c].w, acc);
            }
            s[r] = acc;
        }
#pragma unroll
        for (int m = 1; m < 64; m <<= 1) {
#pragma unroll
            for (int r = 0; r < 8; ++r) s[r] += __shfl_xor(s[r], m, 64);
        }
        if (lane == 0) {
#pragma unroll
            for (int r = 0; r < 8; ++r) {
                float v = s[r] + (bias ? bias[o0 + r] : 0.f);
                if (ACT) v = gelu_exact(v);
                out[(b0 + bi) * ldo + o0 + r] = v;
            }
        }
    }
}

// K1: enc1 (512 waves) + Ea (1024) + Eb (1024) + action->x copy (32) = 2592 waves = 648 blocks
__global__ void __launch_bounds__(256) front_kernel(
    const float* __restrict__ obs, const float* __restrict__ enc_w1,
    const float* __restrict__ enc_b1, float* __restrict__ h1,
    const float* __restrict__ embed, const float* __restrict__ sc_w1,
    const float* __restrict__ sc_b1, float* __restrict__ Ea, float* __restrict__ Eb,
    const float* __restrict__ action, float* __restrict__ x) {
    int wid = blockIdx.x * 4 + (threadIdx.x >> 6);
    int lane = threadIdx.x & 63;
    if (wid < 512) {
        wgemm<3, 1>(wid, obs, 768, enc_w1, 768, enc_b1, h1, 1024, 128);
    } else if (wid < 1536) {
        wgemm<2, 0>(wid - 512, embed, 512, sc_w1, 1536, sc_b1, Ea, 1024, 128);
    } else if (wid < 2560) {
        wgemm<2, 0>(wid - 1536, embed, 512, sc_w1 + 512, 1536, nullptr, Eb, 1024, 128);
    } else {
        int b = wid - 2560;  // 32 waves, one per batch row
        const float4* af = reinterpret_cast<const float4*>(action) + b * 128;
        float4* xf = reinterpret_cast<float4*>(x) + b * 256 + 128;
        xf[lane] = af[lane];
        xf[64 + lane] = af[64 + lane];
    }
}

// K2: enc2 -> x[:, :512]. 256 waves = 64 blocks
__global__ void __launch_bounds__(256) enc2_kernel(
    const float* __restrict__ h1, const float* __restrict__ enc_w2,
    const float* __restrict__ enc_b2, float* __restrict__ x) {
    int wid = blockIdx.x * 4 + (threadIdx.x >> 6);
    wgemm<4, 0>(wid, h1, 1024, enc_w2, 1024, enc_b2, x, 1024, 64);
}

// K3: gi = x @ wih^T + bih. 768 waves = 192 blocks
__global__ void __launch_bounds__(256) gi_kernel(
    const float* __restrict__ x, const float* __restrict__ wih,
    const float* __restrict__ bih, float* __restrict__ gi) {
    int wid = blockIdx.x * 4 + (threadIdx.x >> 6);
    wgemm<4, 0>(wid, x, 1024, wih, 1024, bih, gi, 1536, 192);
}

// K4: GRU elementwise (h0 = 0 => gh = bhh). 64 blocks
__global__ void __launch_bounds__(256) gru_kernel(
    const float* __restrict__ gi, const float* __restrict__ bhh,
    const float* __restrict__ action,
    float* __restrict__ h, float* __restrict__ ha) {
    int tid = blockIdx.x * 256 + threadIdx.x;  // 16384
    int b = tid >> 9;
    int o = tid & 511;
    const float* g = gi + b * 1536;
    float r = 1.f / (1.f + expf(-(g[o] + bhh[o])));
    float u = 1.f / (1.f + expf(-(g[512 + o] + bhh[512 + o])));
    float n = tanhf(g[1024 + o] + r * bhh[1024 + o]);
    float hv = (1.f - u) * n;
    h[tid] = hv;
    ha[tid] = hv + action[tid];
}

// K5: dec (384 waves) + rs1 (256) + Cc (512) = 1152 waves = 288 blocks
__global__ void __launch_bounds__(256) mid_kernel(
    const float* __restrict__ h, const float* __restrict__ ha,
    const float* __restrict__ dec_w, const float* __restrict__ dec_b, float* __restrict__ pred,
    const float* __restrict__ rs_w1, const float* __restrict__ rs_b1, float* __restrict__ r1,
    const float* __restrict__ sc_w1, float* __restrict__ Cc) {
    int wid = blockIdx.x * 4 + (threadIdx.x >> 6);
    if (wid < 384) {
        wgemm<2, 0>(wid, h, 512, dec_w, 512, dec_b, pred, 768, 96);
    } else if (wid < 640) {
        wgemm<2, 1>(wid - 384, h, 512, rs_w1, 512, rs_b1, r1, 512, 64);
    } else {
        wgemm<2, 0>(wid - 640, ha, 512, sc_w1 + 1024, 1536, nullptr, Cc, 1024, 128);
    }
}

// K6: score (2048 blk) + rs2 (64 blk = 256 waves)
__global__ void __launch_bounds__(256) score_rs2_kernel(
    const float* __restrict__ Ea, const float* __restrict__ Eb,
    const float* __restrict__ Cc, const float* __restrict__ w2,
    const float* __restrict__ b2, float* __restrict__ graph,
    const float* __restrict__ r1, const float* __restrict__ rs_w2,
    const float* __restrict__ rs_b2, float* __restrict__ reasoning) {
    int blk = blockIdx.x;
    if (blk >= 2048) {
        int wid = (blk - 2048) * 4 + (threadIdx.x >> 6);
        wgemm<2, 0>(wid, r1, 512, rs_w2, 512, rs_b2, reasoning, 512, 64);
        return;
    }
    int i = blk >> 5;
    int j0 = (blk & 31) << 1;
    int lane = threadIdx.x & 63;
    int wave = threadIdx.x >> 6;
    int d0 = lane << 4;

    const float4* Ea4  = reinterpret_cast<const float4*>(Ea + i * 1024 + d0);
    const float4* Eb04 = reinterpret_cast<const float4*>(Eb + j0 * 1024 + d0);
    const float4* Eb14 = reinterpret_cast<const float4*>(Eb + (j0 + 1) * 1024 + d0);
    const float4* W4   = reinterpret_cast<const float4*>(w2 + d0);

    float basea[16], baseb[16], wv[16];
#pragma unroll
    for (int c = 0; c < 4; ++c) {
        float4 e  = Ea4[c];
        float4 f0 = Eb04[c];
        float4 f1 = Eb14[c];
        float4 w  = W4[c];
        basea[4 * c + 0] = e.x + f0.x; basea[4 * c + 1] = e.y + f0.y;
        basea[4 * c + 2] = e.z + f0.z; basea[4 * c + 3] = e.w + f0.w;
        baseb[4 * c + 0] = e.x + f1.x; baseb[4 * c + 1] = e.y + f1.y;
        baseb[4 * c + 2] = e.z + f1.z; baseb[4 * c + 3] = e.w + f1.w;
        wv[4 * c + 0] = w.x; wv[4 * c + 1] = w.y;
        wv[4 * c + 2] = w.z; wv[4 * c + 3] = w.w;
    }

    float bsc = b2[0];
    float gsum0 = 0.f, gsum1 = 0.f;
    const float4* p = reinterpret_cast<const float4*>(Cc + (wave * 8) * 1024 + d0);
    float4 n0 = p[0], n1 = p[1], n2 = p[2], n3 = p[3];

    for (int r = 0; r < 8; ++r) {
        float cc[16];
        cc[0] = n0.x; cc[1] = n0.y; cc[2]  = n0.z; cc[3]  = n0.w;
        cc[4] = n1.x; cc[5] = n1.y; cc[6]  = n1.z; cc[7]  = n1.w;
        cc[8] = n2.x; cc[9] = n2.y; cc[10] = n2.z; cc[11] = n2.w;
        cc[12] = n3.x; cc[13] = n3.y; cc[14] = n3.z; cc[15] = n3.w;
        if (r < 7) {
            const float4* q = reinterpret_cast<const float4*>(Cc + (wave * 8 + r + 1) * 1024 + d0);
            n0 = q[0]; n1 = q[1]; n2 = q[2]; n3 = q[3];
        }
        float s0 = 0.f, s1 = 0.f;
#pragma unroll
        for (int e = 0; e < 16; ++e) {
            float c = cc[e], w = wv[e];
            s0 = fmaf(gelu_fast(c + basea[e]), w, s0);
            s1 = fmaf(gelu_fast(c + baseb[e]), w, s1);
        }
#pragma unroll
        for (int m = 32; m >= 1; m >>= 1) {
            s0 += __shfl_xor(s0, m, 64);
            s1 += __shfl_xor(s1, m, 64);
        }
        if (lane == 0) {
            gsum0 += sigmoidf_fast(s0 + bsc);
            gsum1 += sigmoidf_fast(s1 + bsc);
        }
    }

    __shared__ float red[4][2];
    if (lane == 0) { red[wave][0] = gsum0; red[wave][1] = gsum1; }
    __syncthreads();
    if (threadIdx.x == 0) {
        graph[i * 64 + j0]     = (red[0][0] + red[1][0] + red[2][0] + red[3][0]) * 0.03125f;
        graph[i * 64 + j0 + 1] = (red[0][1] + red[1][1] + red[2][1] + red[3][1]) * 0.03125f;
    }
}

extern "C" void kernel_launch(void* const* d_in, const int* in_sizes, int n_in,
                              void* d_out, int out_size, void* d_ws, size_t ws_size,
                              hipStream_t stream) {
    const float* obs     = (const float*)d_in[0];
    const float* action  = (const float*)d_in[1];
    const float* embed   = (const float*)d_in[2];
    const float* sc_w1   = (const float*)d_in[3];
    const float* sc_b1   = (const float*)d_in[4];
    const float* sc_w2   = (const float*)d_in[5];
    const float* sc_b2   = (const float*)d_in[6];
    const float* enc_w1  = (const float*)d_in[7];
    const float* enc_b1  = (const float*)d_in[8];
    const float* enc_w2  = (const float*)d_in[9];
    const float* enc_b2  = (const float*)d_in[10];
    const float* gru_wih = (const float*)d_in[11];
    const float* gru_bih = (const float*)d_in[13];
    const float* gru_bhh = (const float*)d_in[14];
    const float* dec_w   = (const float*)d_in[15];
    const float* dec_b   = (const float*)d_in[16];
    const float* rs_w1   = (const float*)d_in[17];
    const float* rs_b1   = (const float*)d_in[18];
    const float* rs_w2   = (const float*)d_in[19];
    const float* rs_b2   = (const float*)d_in[20];

    float* ws = (float*)d_ws;
    float* x  = ws + 0;            // 32x1024
    float* h1 = ws + 32768;        // 32x1024
    float* gi = ws + 65536;        // 32x1536
    float* ha = ws + 114688;       // 32x512
    float* r1 = ws + 131072;       // 32x512
    float* Cc = ws + 147456;       // 32x1024
    float* Ea = ws + 180224;       // 64x1024
    float* Eb = ws + 245760;       // 64x1024

    float* h_out     = (float*)d_out;
    float* pred      = h_out + 16384;
    float* graph     = h_out + 40960;
    float* reasoning = h_out + 45056;

    front_kernel<<<648, 256, 0, stream>>>(obs, enc_w1, enc_b1, h1,
                                          embed, sc_w1, sc_b1, Ea, Eb, action, x);
    enc2_kernel<<<64, 256, 0, stream>>>(h1, enc_w2, enc_b2, x);
    gi_kernel<<<192, 256, 0, stream>>>(x, gru_wih, gru_bih, gi);
    gru_kernel<<<64, 256, 0, stream>>>(gi, gru_bhh, action, h_out, ha);
    mid_kernel<<<288, 256, 0, stream>>>(h_out, ha, dec_w, dec_b, pred,
                                        rs_w1, rs_b1, r1, sc_w1, Cc);
    score_rs2_kernel<<<2112, 256, 0, stream>>>(Ea, Eb, Cc, sc_w2, sc_b2, graph,
                                               r1, rs_w2, rs_b2, reasoning);
}

// Round 4
// 215.308 us; speedup vs baseline: 1.6562x; 1.0554x over previous
//
#include <hip/hip_runtime.h>
#include <math.h>

// B=32, OBS=768, D=512, V=64
// Outputs (f32): h[32*512] | pred[32*768] | graph[64*64] | reasoning[32*512]

#if __has_builtin(__builtin_amdgcn_exp2f)
#define EXP2F __builtin_amdgcn_exp2f
#else
#define EXP2F exp2f
#endif

__device__ __forceinline__ float gelu_exact(float x) {
    return 0.5f * x * (1.f + erff(x * 0.70710678118654752f));
}

__device__ __forceinline__ float sigmoidf_fast(float v) {
    return 1.f / (1.f + __expf(-v));
}

// Wave-tile GEMM: one wave computes out[b0..b0+7][o0..o0+7] = act(A[b,:]·W[o,:] + bias[o]).
// K = NF4*256 floats. Lane owns float4 indices {c*64+lane}: all loads coalesced (1KB/instr).
template<int NF4, int ACT>
__device__ __forceinline__ void wgemm(int wid,
        const float* __restrict__ A, int lda,
        const float* __restrict__ W, int ldw,
        const float* __restrict__ bias,
        float* __restrict__ out, int ldo,
        int oblocks) {
    int lane = threadIdx.x & 63;
    int oblock = wid % oblocks;
    int bgroup = wid / oblocks;
    int o0 = oblock * 8, b0 = bgroup * 8;

    float4 w[8][NF4];
#pragma unroll
    for (int r = 0; r < 8; ++r) {
        const float4* wr = reinterpret_cast<const float4*>(W + (o0 + r) * ldw);
#pragma unroll
        for (int c = 0; c < NF4; ++c) w[r][c] = wr[c * 64 + lane];
    }

#pragma unroll 2
    for (int bi = 0; bi < 8; ++bi) {
        const float4* ar = reinterpret_cast<const float4*>(A + (b0 + bi) * lda);
        float4 a[NF4];
#pragma unroll
        for (int c = 0; c < NF4; ++c) a[c] = ar[c * 64 + lane];
        float s[8];
#pragma unroll
        for (int r = 0; r < 8; ++r) {
            float acc = 0.f;
#pragma unroll
            for (int c = 0; c < NF4; ++c) {
                acc = fmaf(a[c].x, w[r][c].x, acc);
                acc = fmaf(a[c].y, w[r][c].y, acc);
                acc = fmaf(a[c].z, w[r][c].z, acc);
                acc = fmaf(a[c].w, w[r][c].w, acc);
            }
            s[r] = acc;
        }
#pragma unroll
        for (int m = 1; m < 64; m <<= 1) {
#pragma unroll
            for (int r = 0; r < 8; ++r) s[r] += __shfl_xor(s[r], m, 64);
        }
        if (lane == 0) {
#pragma unroll
            for (int r = 0; r < 8; ++r) {
                float v = s[r] + (bias ? bias[o0 + r] : 0.f);
                if (ACT) v = gelu_exact(v);
                out[(b0 + bi) * ldo + o0 + r] = v;
            }
        }
    }
}

// K1: enc1 (512 waves) + Ea (1024) + Eb (1024) + action->x copy (32) = 2592 waves = 648 blocks
__global__ void __launch_bounds__(256) front_kernel(
    const float* __restrict__ obs, const float* __restrict__ enc_w1,
    const float* __restrict__ enc_b1, float* __restrict__ h1,
    const float* __restrict__ embed, const float* __restrict__ sc_w1,
    const float* __restrict__ sc_b1, float* __restrict__ Ea, float* __restrict__ Eb,
    const float* __restrict__ action, float* __restrict__ x) {
    int wid = blockIdx.x * 4 + (threadIdx.x >> 6);
    int lane = threadIdx.x & 63;
    if (wid < 512) {
        wgemm<3, 1>(wid, obs, 768, enc_w1, 768, enc_b1, h1, 1024, 128);
    } else if (wid < 1536) {
        wgemm<2, 0>(wid - 512, embed, 512, sc_w1, 1536, sc_b1, Ea, 1024, 128);
    } else if (wid < 2560) {
        wgemm<2, 0>(wid - 1536, embed, 512, sc_w1 + 512, 1536, nullptr, Eb, 1024, 128);
    } else {
        int b = wid - 2560;  // 32 waves, one per batch row
        const float4* af = reinterpret_cast<const float4*>(action) + b * 128;
        float4* xf = reinterpret_cast<float4*>(x) + b * 256 + 128;
        xf[lane] = af[lane];
        xf[64 + lane] = af[64 + lane];
    }
}

// K2: enc2 -> x[:, :512]. 256 waves = 64 blocks
__global__ void __launch_bounds__(256) enc2_kernel(
    const float* __restrict__ h1, const float* __restrict__ enc_w2,
    const float* __restrict__ enc_b2, float* __restrict__ x) {
    int wid = blockIdx.x * 4 + (threadIdx.x >> 6);
    wgemm<4, 0>(wid, h1, 1024, enc_w2, 1024, enc_b2, x, 1024, 64);
}

// K3: gi GEMM + GRU fused. Wave = o-pair (2 o's x 3 gates = 6 W rows) x 8 b rows.
// 256 opairs x 4 bgroups = 1024 waves = 256 blocks. h0 = 0 => gh = bhh.
__global__ void __launch_bounds__(256) gigru_kernel(
    const float* __restrict__ x, const float* __restrict__ wih,
    const float* __restrict__ bih, const float* __restrict__ bhh,
    const float* __restrict__ action, float* __restrict__ h, float* __restrict__ ha) {
    int wid = blockIdx.x * 4 + (threadIdx.x >> 6);
    int lane = threadIdx.x & 63;
    int opair = wid & 255;
    int bg = wid >> 8;
    int o0 = opair * 2, b0 = bg * 8;

    int rows[6] = {o0, o0 + 1, 512 + o0, 512 + o0 + 1, 1024 + o0, 1024 + o0 + 1};
    float4 w[6][4];
#pragma unroll
    for (int r = 0; r < 6; ++r) {
        const float4* wr = reinterpret_cast<const float4*>(wih + rows[r] * 1024);
#pragma unroll
        for (int c = 0; c < 4; ++c) w[r][c] = wr[c * 64 + lane];
    }
    // bias sums (uniform, broadcast loads)
    float bsr0 = bih[o0] + bhh[o0],         bsr1 = bih[o0 + 1] + bhh[o0 + 1];
    float bsu0 = bih[512 + o0] + bhh[512 + o0], bsu1 = bih[513 + o0] + bhh[513 + o0];
    float bin0 = bih[1024 + o0], bin1 = bih[1025 + o0];
    float bhn0 = bhh[1024 + o0], bhn1 = bhh[1025 + o0];

#pragma unroll 2
    for (int bi = 0; bi < 8; ++bi) {
        const float4* ar = reinterpret_cast<const float4*>(x + (b0 + bi) * 1024);
        float4 a[4];
#pragma unroll
        for (int c = 0; c < 4; ++c) a[c] = ar[c * 64 + lane];
        float s[6];
#pragma unroll
        for (int r = 0; r < 6; ++r) {
            float acc = 0.f;
#pragma unroll
            for (int c = 0; c < 4; ++c) {
                acc = fmaf(a[c].x, w[r][c].x, acc);
                acc = fmaf(a[c].y, w[r][c].y, acc);
                acc = fmaf(a[c].z, w[r][c].z, acc);
                acc = fmaf(a[c].w, w[r][c].w, acc);
            }
            s[r] = acc;
        }
#pragma unroll
        for (int m = 1; m < 64; m <<= 1) {
#pragma unroll
            for (int r = 0; r < 6; ++r) s[r] += __shfl_xor(s[r], m, 64);
        }
        if (lane == 0) {
            int b = b0 + bi;
            float r0 = sigmoidf_fast(s[0] + bsr0);
            float r1 = sigmoidf_fast(s[1] + bsr1);
            float u0 = sigmoidf_fast(s[2] + bsu0);
            float u1 = sigmoidf_fast(s[3] + bsu1);
            float n0 = tanhf(s[4] + bin0 + r0 * bhn0);
            float n1 = tanhf(s[5] + bin1 + r1 * bhn1);
            float hv0 = (1.f - u0) * n0;
            float hv1 = (1.f - u1) * n1;
            h[b * 512 + o0] = hv0;
            h[b * 512 + o0 + 1] = hv1;
            ha[b * 512 + o0] = hv0 + action[b * 512 + o0];
            ha[b * 512 + o0 + 1] = hv1 + action[b * 512 + o0 + 1];
        }
    }
}

// K4: dec (384 waves) + rs1 (256) + Cc (512) = 1152 waves = 288 blocks
__global__ void __launch_bounds__(256) mid_kernel(
    const float* __restrict__ h, const float* __restrict__ ha,
    const float* __restrict__ dec_w, const float* __restrict__ dec_b, float* __restrict__ pred,
    const float* __restrict__ rs_w1, const float* __restrict__ rs_b1, float* __restrict__ r1,
    const float* __restrict__ sc_w1, float* __restrict__ Cc) {
    int wid = blockIdx.x * 4 + (threadIdx.x >> 6);
    if (wid < 384) {
        wgemm<2, 0>(wid, h, 512, dec_w, 512, dec_b, pred, 768, 96);
    } else if (wid < 640) {
        wgemm<2, 1>(wid - 384, h, 512, rs_w1, 512, rs_b1, r1, 512, 64);
    } else {
        wgemm<2, 0>(wid - 640, ha, 512, sc_w1 + 1024, 1536, nullptr, Cc, 1024, 128);
    }
}

// K5: score (2048 blk) + rs2 (64 blk). Per score block: wave w -> b in [8w,8w+8),
// lane -> d in [16*lane,16*lane+16). gelu = x*sigmoid(1.702x), exp2-folded:
// gelu(x) ~= x / (1 + 2^(-2.4554274x))
__global__ void __launch_bounds__(256) score_rs2_kernel(
    const float* __restrict__ Ea, const float* __restrict__ Eb,
    const float* __restrict__ Cc, const float* __restrict__ w2,
    const float* __restrict__ b2, float* __restrict__ graph,
    const float* __restrict__ r1, const float* __restrict__ rs_w2,
    const float* __restrict__ rs_b2, float* __restrict__ reasoning) {
    int blk = blockIdx.x;
    if (blk >= 2048) {
        int wid = (blk - 2048) * 4 + (threadIdx.x >> 6);
        wgemm<2, 0>(wid, r1, 512, rs_w2, 512, rs_b2, reasoning, 512, 64);
        return;
    }
    int i = blk >> 5;
    int j0 = (blk & 31) << 1;
    int lane = threadIdx.x & 63;
    int wave = threadIdx.x >> 6;
    int d0 = lane << 4;

    const float4* Ea4  = reinterpret_cast<const float4*>(Ea + i * 1024 + d0);
    const float4* Eb04 = reinterpret_cast<const float4*>(Eb + j0 * 1024 + d0);
    const float4* Eb14 = reinterpret_cast<const float4*>(Eb + (j0 + 1) * 1024 + d0);
    const float4* W4   = reinterpret_cast<const float4*>(w2 + d0);

    float basea[16], baseb[16], wv[16];
#pragma unroll
    for (int c = 0; c < 4; ++c) {
        float4 e  = Ea4[c];
        float4 f0 = Eb04[c];
        float4 f1 = Eb14[c];
        float4 w  = W4[c];
        basea[4 * c + 0] = e.x + f0.x; basea[4 * c + 1] = e.y + f0.y;
        basea[4 * c + 2] = e.z + f0.z; basea[4 * c + 3] = e.w + f0.w;
        baseb[4 * c + 0] = e.x + f1.x; baseb[4 * c + 1] = e.y + f1.y;
        baseb[4 * c + 2] = e.z + f1.z; baseb[4 * c + 3] = e.w + f1.w;
        wv[4 * c + 0] = w.x; wv[4 * c + 1] = w.y;
        wv[4 * c + 2] = w.z; wv[4 * c + 3] = w.w;
    }

    const float NK = -2.4554274f;  // -1.702 * log2(e)
    float bsc = b2[0];
    float gsum0 = 0.f, gsum1 = 0.f;
    const float4* p = reinterpret_cast<const float4*>(Cc + (wave * 8) * 1024 + d0);
    float4 n0 = p[0], n1 = p[1], n2 = p[2], n3 = p[3];

    for (int r = 0; r < 8; ++r) {
        float cc[16];
        cc[0] = n0.x; cc[1] = n0.y; cc[2]  = n0.z; cc[3]  = n0.w;
        cc[4] = n1.x; cc[5] = n1.y; cc[6]  = n1.z; cc[7]  = n1.w;
        cc[8] = n2.x; cc[9] = n2.y; cc[10] = n2.z; cc[11] = n2.w;
        cc[12] = n3.x; cc[13] = n3.y; cc[14] = n3.z; cc[15] = n3.w;
        if (r < 7) {
            const float4* q = reinterpret_cast<const float4*>(Cc + (wave * 8 + r + 1) * 1024 + d0);
            n0 = q[0]; n1 = q[1]; n2 = q[2]; n3 = q[3];
        }
        float s0 = 0.f, s1 = 0.f;
#pragma unroll
        for (int e = 0; e < 16; ++e) {
            float c = cc[e], w = wv[e];
            float xa = c + basea[e];
            float xb = c + baseb[e];
            float ta = EXP2F(xa * NK);
            float tb = EXP2F(xb * NK);
            s0 = fmaf(xa * __builtin_amdgcn_rcpf(1.f + ta), w, s0);
            s1 = fmaf(xb * __builtin_amdgcn_rcpf(1.f + tb), w, s1);
        }
#pragma unroll
        for (int m = 32; m >= 1; m >>= 1) {
            s0 += __shfl_xor(s0, m, 64);
            s1 += __shfl_xor(s1, m, 64);
        }
        if (lane == 0) {
            gsum0 += sigmoidf_fast(s0 + bsc);
            gsum1 += sigmoidf_fast(s1 + bsc);
        }
    }

    __shared__ float red[4][2];
    if (lane == 0) { red[wave][0] = gsum0; red[wave][1] = gsum1; }
    __syncthreads();
    if (threadIdx.x == 0) {
        graph[i * 64 + j0]     = (red[0][0] + red[1][0] + red[2][0] + red[3][0]) * 0.03125f;
        graph[i * 64 + j0 + 1] = (red[0][1] + red[1][1] + red[2][1] + red[3][1]) * 0.03125f;
    }
}

extern "C" void kernel_launch(void* const* d_in, const int* in_sizes, int n_in,
                              void* d_out, int out_size, void* d_ws, size_t ws_size,
                              hipStream_t stream) {
    const float* obs     = (const float*)d_in[0];
    const float* action  = (const float*)d_in[1];
    const float* embed   = (const float*)d_in[2];
    const float* sc_w1   = (const float*)d_in[3];
    const float* sc_b1   = (const float*)d_in[4];
    const float* sc_w2   = (const float*)d_in[5];
    const float* sc_b2   = (const float*)d_in[6];
    const float* enc_w1  = (const float*)d_in[7];
    const float* enc_b1  = (const float*)d_in[8];
    const float* enc_w2  = (const float*)d_in[9];
    const float* enc_b2  = (const float*)d_in[10];
    const float* gru_wih = (const float*)d_in[11];
    const float* gru_bih = (const float*)d_in[13];
    const float* gru_bhh = (const float*)d_in[14];
    const float* dec_w   = (const float*)d_in[15];
    const float* dec_b   = (const float*)d_in[16];
    const float* rs_w1   = (const float*)d_in[17];
    const float* rs_b1   = (const float*)d_in[18];
    const float* rs_w2   = (const float*)d_in[19];
    const float* rs_b2   = (const float*)d_in[20];

    float* ws = (float*)d_ws;
    float* x  = ws + 0;            // 32x1024
    float* h1 = ws + 32768;        // 32x1024
    float* ha = ws + 114688;       // 32x512
    float* r1 = ws + 131072;       // 32x512
    float* Cc = ws + 147456;       // 32x1024
    float* Ea = ws + 180224;       // 64x1024
    float* Eb = ws + 245760;       // 64x1024

    float* h_out     = (float*)d_out;
    float* pred      = h_out + 16384;
    float* graph     = h_out + 40960;
    float* reasoning = h_out + 45056;

    front_kernel<<<648, 256, 0, stream>>>(obs, enc_w1, enc_b1, h1,
                                          embed, sc_w1, sc_b1, Ea, Eb, action, x);
    enc2_kernel<<<64, 256, 0, stream>>>(h1, enc_w2, enc_b2, x);
    gigru_kernel<<<256, 256, 0, stream>>>(x, gru_wih, gru_bih, gru_bhh, action, h_out, ha);
    mid_kernel<<<288, 256, 0, stream>>>(h_out, ha, dec_w, dec_b, pred,
                                        rs_w1, rs_b1, r1, sc_w1, Cc);
    score_rs2_kernel<<<2112, 256, 0, stream>>>(Ea, Eb, Cc, sc_w2, sc_b2, graph,
                                               r1, rs_w2, rs_b2, reasoning);
}